// Round 7
// baseline (349.011 us; speedup 1.0000x reference)
//
#include <hip/hip_runtime.h>
#include <hip/hip_bf16.h>

typedef float f32x4 __attribute__((ext_vector_type(4)));

#define B_  8192
#define H_  128
#define NW  1106    // G + 3*W
#define NC  640     // gates gemm output cols (r,u,s,gi_n,gh_n)
#define KK  256

static const size_t N4TOT = (size_t)NW * NW * H_ / 4;   // 39,143,552 float4s

// copy-slice boundaries (float4 units)
#define SL_A 1500000UL
#define SL_B 9000000UL
#define SL_C 19000000UL

#define PREP_CB  256
#define PREP_CPB 1024
#define GEMM_CPB 1024
#define MEGA_CPB 6144
#define DRAIN_BLKS 2048

__device__ __forceinline__ float sigmf(float x) { return 1.0f / (1.0f + expf(-x)); }

__device__ __forceinline__ void copy_span(const f32x4* __restrict__ src,
                                          f32x4* __restrict__ dst,
                                          size_t lo, size_t hi,
                                          size_t ctid, size_t cthreads) {
    for (size_t i = lo + ctid; i < hi; i += cthreads) {
        f32x4 v = __builtin_nontemporal_load(src + i);
        __builtin_nontemporal_store(v, dst + i);
    }
}

// ---------------------------------------------------------------------------
// Prep: Wbig (640x256), wP (w_out packed k-quad-major), winner=-1; + slice A
// Wbig rows: [0,128)=r (wih|whh), [128,256)=u, [256,384)=s (w rows 384..512),
// [384,512)=gi_n (wih_n|0), [512,640)=gh_n (0|whh_n)
// wP[(kq*128+col)*4 + j] = w_out[col*256 + 4*kq + j]
// ---------------------------------------------------------------------------
__global__ __launch_bounds__(256) void prep_kernel(
    const float* __restrict__ w_ih, const float* __restrict__ w_hh,
    const float* __restrict__ w_out,
    float* __restrict__ Wbig, float* __restrict__ wP, int* __restrict__ winner,
    const f32x4* __restrict__ src, f32x4* __restrict__ dst, size_t lo, size_t hi) {
    int bid = blockIdx.x, tid = threadIdx.x;
    if (bid >= PREP_CB) {
        size_t ctid = (size_t)(bid - PREP_CB) * 256 + tid;
        copy_span(src, dst, lo, hi, ctid, (size_t)(gridDim.x - PREP_CB) * 256);
        return;
    }
    size_t stride = (size_t)PREP_CB * 256;
    size_t id0 = (size_t)bid * 256 + tid;
    for (size_t i = id0; i < (size_t)NC * 256; i += stride) {
        int j = (int)(i >> 8); int k = (int)(i & 255);
        float v;
        if (j < 256) {
            v = (k < 128) ? w_ih[j * 128 + k] : w_hh[j * 128 + (k - 128)];
        } else if (j < 384) {
            int r = 384 + (j - 256);
            v = (k < 128) ? w_ih[r * 128 + k] : w_hh[r * 128 + (k - 128)];
        } else if (j < 512) {
            int r = 256 + (j - 384);
            v = (k < 128) ? w_ih[r * 128 + k] : 0.0f;
        } else {
            int r = 256 + (j - 512);
            v = (k < 128) ? 0.0f : w_hh[r * 128 + (k - 128)];
        }
        Wbig[i] = v;
    }
    for (size_t i = id0; i < (size_t)H_ * KK; i += stride) {   // 32768
        int col = (int)(i >> 8); int k = (int)(i & 255);
        wP[(size_t)((k >> 2) * 128 + col) * 4 + (k & 3)] = w_out[i];
    }
    for (size_t i = id0; i < (size_t)NW * NW; i += stride) winner[i] = -1;
}

// ---------------------------------------------------------------------------
// Gates GEMM: Cbuf = [xf|hx] @ Wbig^T.  A staged transposed (b128 reads).
// Extra blocks: first 32 do winner atomicMax; all do copy slice.
// ---------------------------------------------------------------------------
__global__ __launch_bounds__(256) void gemm_abt(
    const float* __restrict__ A0, const float* __restrict__ A1,
    const float* __restrict__ Bw, float* __restrict__ Cc,
    const int* __restrict__ gidx, int* __restrict__ winner,
    const f32x4* __restrict__ src, f32x4* __restrict__ dst, size_t lo, size_t hi) {
    __shared__ float As[32][68];
    __shared__ float Ws[32][132];
    int bid = blockIdx.x, tid = threadIdx.x;
    if (bid >= 640) {
        int rel = bid - 640;
        if (rel < 32) {
            int b = rel * 256 + tid;
            int gx = gidx[2 * b] + 2, gy = gidx[2 * b + 1] + 2;
            atomicMax(&winner[gx * NW + gy], b);
        }
        size_t ctid = (size_t)rel * 256 + tid;
        copy_span(src, dst, lo, hi, ctid, (size_t)(gridDim.x - 640) * 256);
        return;
    }
    int bx = bid & 127, by = bid >> 7;
    int tn = tid & 15, tm = tid >> 4;
    size_t m0 = (size_t)bx * 64;
    int n0 = by * 128;
    float acc[4][8];
#pragma unroll
    for (int i = 0; i < 4; ++i)
#pragma unroll
        for (int j = 0; j < 8; ++j) acc[i][j] = 0.0f;

    for (int k0 = 0; k0 < KK; k0 += 32) {
        const float* a0 = (k0 < 128) ? A0 : A1;
        int koff = k0 & 127;
        __syncthreads();
#pragma unroll
        for (int p = 0; p < 2; ++p) {        // A tile 64x32, transposed stage
            int f = tid + 256 * p; int r = f >> 3, cq = f & 7;
            float4 v = *(const float4*)(a0 + (size_t)(m0 + r) * 128 + koff + 4 * cq);
            As[4 * cq + 0][r] = v.x; As[4 * cq + 1][r] = v.y;
            As[4 * cq + 2][r] = v.z; As[4 * cq + 3][r] = v.w;
        }
#pragma unroll
        for (int p = 0; p < 4; ++p) {        // B tile 128x32, transposed stage
            int f = tid + 256 * p; int c = f >> 3, cq = f & 7;
            float4 v = *(const float4*)(Bw + (size_t)(n0 + c) * KK + (k0 + 4 * cq));
            Ws[4 * cq + 0][c] = v.x; Ws[4 * cq + 1][c] = v.y;
            Ws[4 * cq + 2][c] = v.z; Ws[4 * cq + 3][c] = v.w;
        }
        __syncthreads();
#pragma unroll
        for (int kk = 0; kk < 32; ++kk) {
            float4 a4 = *(const float4*)(&As[kk][4 * tm]);
            float4 w0 = *(const float4*)(&Ws[kk][4 * tn]);
            float4 w1 = *(const float4*)(&Ws[kk][64 + 4 * tn]);
            float a_[4] = {a4.x, a4.y, a4.z, a4.w};
#pragma unroll
            for (int i = 0; i < 4; ++i) {
                acc[i][0] += a_[i] * w0.x; acc[i][1] += a_[i] * w0.y;
                acc[i][2] += a_[i] * w0.z; acc[i][3] += a_[i] * w0.w;
                acc[i][4] += a_[i] * w1.x; acc[i][5] += a_[i] * w1.y;
                acc[i][6] += a_[i] * w1.z; acc[i][7] += a_[i] * w1.w;
            }
        }
    }
#pragma unroll
    for (int i = 0; i < 4; ++i) {
        size_t row = m0 + 4 * tm + i;
        float4 v0 = make_float4(acc[i][0], acc[i][1], acc[i][2], acc[i][3]);
        float4 v1 = make_float4(acc[i][4], acc[i][5], acc[i][6], acc[i][7]);
        *(float4*)(Cc + row * NC + n0 + 4 * tn) = v0;
        *(float4*)(Cc + row * NC + n0 + 64 + 4 * tn) = v1;
    }
}

// ---------------------------------------------------------------------------
// MEGA: gates + attention + out-GEMV + GRU combine + hyy + direct scatter.
// One wave per b.  Copy blocks (winner-skip: scatter happens in this phase).
// ---------------------------------------------------------------------------
__global__ __launch_bounds__(64) void mega_kernel(
    const float* __restrict__ C, const float* __restrict__ memory,
    const int* __restrict__ gidx, const float* __restrict__ b_ih,
    const float* __restrict__ b_hh, const float* __restrict__ wP,
    const float* __restrict__ b_out, const float* __restrict__ hx,
    const int* __restrict__ winner, float* __restrict__ hyy,
    float* __restrict__ newmem,
    const f32x4* __restrict__ src, f32x4* __restrict__ dst, size_t lo, size_t hi) {
    int bid = blockIdx.x;
    int t = threadIdx.x;
    if (bid >= B_) {
        size_t ctid = (size_t)(bid - B_) * 64 + t;
        size_t nthr = (size_t)(gridDim.x - B_) * 64;
        for (size_t i = lo + ctid; i < hi; i += nthr) {
            if (winner[i >> 5] < 0) {
                f32x4 v = __builtin_nontemporal_load(src + i);
                __builtin_nontemporal_store(v, dst + i);
            }
        }
        return;
    }
    __shared__ float mq[256];
    int b = bid;
    int t1 = t + 64;
    const float* Crow = C + (size_t)b * NC;
    float r0 = sigmf(Crow[t]        + b_ih[t]        + b_hh[t]);
    float r1 = sigmf(Crow[t1]       + b_ih[t1]       + b_hh[t1]);
    float u0 = sigmf(Crow[128 + t]  + b_ih[128 + t]  + b_hh[128 + t]);
    float u1 = sigmf(Crow[128 + t1] + b_ih[128 + t1] + b_hh[128 + t1]);
    float s0 = sigmf(Crow[256 + t]  + b_ih[384 + t]  + b_hh[384 + t]);
    float s1 = sigmf(Crow[256 + t1] + b_ih[384 + t1] + b_hh[384 + t1]);
    float n0 = tanhf(Crow[384 + t]  + b_ih[256 + t]  + r0 * (Crow[512 + t]  + b_hh[256 + t]));
    float n1 = tanhf(Crow[384 + t1] + b_ih[256 + t1] + r1 * (Crow[512 + t1] + b_hh[256 + t1]));

    int gx = gidx[2 * b] + 2, gy = gidx[2 * b + 1] + 2;
    const float* base = memory + ((size_t)gx * NW + gy) * H_ + t;
    float cs0[25], cs1[25];
#pragma unroll
    for (int l = 0; l < 25; ++l) {
        int dx = l / 5 - 2, dy = l % 5 - 2;
        const float* row = base + ((long)dx * NW + dy) * H_;
        cs0[l] = row[0];
        cs1[l] = row[64];
    }
    float sc[25];
#pragma unroll
    for (int l = 0; l < 25; ++l) {
        float p = n0 * cs0[l] + n1 * cs1[l];
#pragma unroll
        for (int w = 1; w < 64; w <<= 1) p += __shfl_xor(p, w, 64);
        sc[l] = p;
    }
    float mx = sc[0];
#pragma unroll
    for (int l = 1; l < 25; ++l) mx = fmaxf(mx, sc[l]);
    float den = 0.0f, mix0 = 0.0f, mix1 = 0.0f;
#pragma unroll
    for (int l = 0; l < 25; ++l) {
        float e = expf(sc[l] - mx);
        den += e;
        mix0 += e * cs0[l];
        mix1 += e * cs1[l];
    }
    float inv = 1.0f / den;
    mix0 *= inv; mix1 *= inv;

    // stage mixq row (mix | q) in LDS for the out-GEMV broadcast
    mq[t] = mix0; mq[64 + t] = mix1; mq[128 + t] = n0; mq[192 + t] = n1;
    __syncthreads();

    // out-GEMV: AC[col] = sum_k mq[k] * w_out[col][k], cols t and t+64
    const f32x4* wp4 = (const f32x4*)wP;
    float acc0 = 0.0f, acc1 = 0.0f;
#pragma unroll 8
    for (int kq = 0; kq < 64; ++kq) {
        f32x4 m4 = *(const f32x4*)(&mq[kq * 4]);
        f32x4 w0 = wp4[kq * 128 + t];
        f32x4 w1 = wp4[kq * 128 + t1];
        acc0 += m4.x * w0.x + m4.y * w0.y + m4.z * w0.z + m4.w * w0.w;
        acc1 += m4.x * w1.x + m4.y * w1.y + m4.z * w1.z + m4.w * w1.w;
    }

    float atten0 = tanhf(acc0 + b_out[t]);
    float atten1 = tanhf(acc1 + b_out[t1]);
    float curr0 = n0 + s0 * atten0;
    float curr1 = n1 + s1 * atten1;
    float hy0 = curr0 + u0 * (hx[(size_t)b * H_ + t]  - curr0);
    float hy1 = curr1 + u1 * (hx[(size_t)b * H_ + t1] - curr1);
    hyy[(size_t)b * H_ + t]  = hy0;
    hyy[(size_t)b * H_ + t1] = hy1;

    size_t cell = (size_t)gx * NW + gy;
    if (winner[cell] == b) {   // direct scatter; copy (this phase + drain) skips
        float m0c = cs0[12], m1c = cs1[12];   // (dx,dy)=(0,0) already gathered
        newmem[cell * H_ + t]  = s0 * m0c + (1.0f - s0) * hy0;
        newmem[cell * H_ + t1] = s1 * m1c + (1.0f - s1) * hy1;
    }
}

// ---------------------------------------------------------------------------
// Drain: winner-skip copy of [lo,hi)
// ---------------------------------------------------------------------------
__global__ __launch_bounds__(256) void drain_kernel(
    const int* __restrict__ winner,
    const f32x4* __restrict__ src, f32x4* __restrict__ dst, size_t lo, size_t hi) {
    size_t gt = (size_t)blockIdx.x * 256 + threadIdx.x;
    size_t nthr = (size_t)gridDim.x * 256;
    for (size_t i = lo + gt; i < hi; i += nthr) {
        if (winner[i >> 5] < 0) {
            f32x4 v = __builtin_nontemporal_load(src + i);
            __builtin_nontemporal_store(v, dst + i);
        }
    }
}

extern "C" void kernel_launch(void* const* d_in, const int* in_sizes, int n_in,
                              void* d_out, int out_size, void* d_ws, size_t ws_size,
                              hipStream_t stream) {
    const float* xf     = (const float*)d_in[0];
    const float* hx     = (const float*)d_in[1];
    const int*   gidx   = (const int*)d_in[2];
    const float* memory = (const float*)d_in[3];
    const float* w_ih   = (const float*)d_in[4];
    const float* w_hh   = (const float*)d_in[5];
    const float* b_ih   = (const float*)d_in[6];
    const float* b_hh   = (const float*)d_in[7];
    const float* w_out  = (const float*)d_in[8];
    const float* b_out  = (const float*)d_in[9];

    float* out    = (float*)d_out;
    float* hyy    = out;
    float* newmem = out + (size_t)B_ * H_;
    const f32x4* src4 = (const f32x4*)memory;
    f32x4*       dst4 = (f32x4*)newmem;

    // ws layout: winner, Wbig, wP, [Cbuf]
    int*   winner = (int*)d_ws;                               // NW*NW
    float* Wbig   = (float*)(winner + (size_t)NW * NW);       // 640*256
    float* wP     = Wbig + (size_t)NC * KK;                   // 128*256
    float* wsCbuf = wP + (size_t)H_ * KK;
    size_t base_bytes = (size_t)((char*)wsCbuf - (char*)d_ws);
    size_t CF = (size_t)B_ * NC;
    bool distributed = (ws_size >= base_bytes + CF * sizeof(float));
    float* Cbuf = distributed ? wsCbuf : newmem;   // fallback stages in newmem

    if (distributed) {
        size_t a1 = SL_A, b1 = a1 + SL_B, c1 = b1 + SL_C;
        prep_kernel<<<PREP_CB + PREP_CPB, 256, 0, stream>>>(
            w_ih, w_hh, w_out, Wbig, wP, winner, src4, dst4, 0, a1);
        gemm_abt<<<640 + GEMM_CPB, 256, 0, stream>>>(
            xf, hx, Wbig, Cbuf, gidx, winner, src4, dst4, a1, b1);
        mega_kernel<<<B_ + MEGA_CPB, 64, 0, stream>>>(
            Cbuf, memory, gidx, b_ih, b_hh, wP, b_out, hx, winner, hyy, newmem,
            src4, dst4, b1, c1);
        drain_kernel<<<DRAIN_BLKS, 256, 0, stream>>>(
            winner, src4, dst4, c1, N4TOT);
    } else {
        // serial: Cbuf staged in newmem; mega scatters BEFORE the drain copy,
        // drain (winner-skip) then fills everything else including ex-Cbuf region
        prep_kernel<<<PREP_CB, 256, 0, stream>>>(
            w_ih, w_hh, w_out, Wbig, wP, winner, src4, dst4, 0, 0);
        gemm_abt<<<640 + 32, 256, 0, stream>>>(
            xf, hx, Wbig, Cbuf, gidx, winner, src4, dst4, 0, 0);
        mega_kernel<<<B_, 64, 0, stream>>>(
            Cbuf, memory, gidx, b_ih, b_hh, wP, b_out, hx, winner, hyy, newmem,
            src4, dst4, 0, 0);
        drain_kernel<<<DRAIN_BLKS, 256, 0, stream>>>(
            winner, src4, dst4, 0, N4TOT);
    }
}